// Round 11
// baseline (80.433 us; speedup 1.0000x reference)
//
#include <hip/hip_runtime.h>
#include <hip/hip_bf16.h>
#include <cstdint>

// out = D^-1/2 (I+A) D^-1/2 X W + b ; N=8192, F=256, ~33 nnz/row, A symmetric.
// Stage 1 (fused): [MFMA GEMM Y=X@W -> bf16, 512 blocks at grid head] ||
//   [upper-triangle A-scan: LDS forward-edge collection, batched mirror
//    scatter, cnt[] = degree].
// Stage 2: ONE ROW PER BLOCK, 4 waves split the neighbor list (stride 4),
//   LDS partial reduce -> shortens the serial gather chain 34 -> ~9.
//   NOTE: spmm launched TWICE this round (idempotent) to measure its cost
//   from dur_us directly.

#define NN 8192
#define FF 256
#define ELLK 128
#define BM 64
#define BN 64
#define NGEMM ((NN / BM) * (FF / BN))   // 512 gemm blocks
#define NSCAN (NN / 2)                  // 4096 scan blocks (row pairs)

typedef short bf16x8 __attribute__((ext_vector_type(8)));
typedef float f32x4  __attribute__((ext_vector_type(4)));

__device__ __forceinline__ float bf2f(unsigned short u) {
    union { unsigned int i; float f; } c; c.i = ((unsigned int)u) << 16; return c.f;
}
__device__ __forceinline__ unsigned short f2bf(float f) {
    union { float f; unsigned int i; } c; c.f = f;
    unsigned int r = c.i + 0x7FFF + ((c.i >> 16) & 1);   // round-to-nearest-even
    return (unsigned short)(r >> 16);
}

// stream row r's strict upper triangle (j > r), appending hits to LDS list
__device__ __forceinline__ void scan_row_upper(const float* __restrict__ A, int r,
                                               unsigned short* __restrict__ loc,
                                               int* __restrict__ lcnt) {
    const uint4* Arow = reinterpret_cast<const uint4*>(A + (size_t)r * NN);
    const int c0 = (r + 1) >> 2;
    for (int c = c0 + threadIdx.x; c < NN / 4; c += 256) {
        uint4 v = Arow[c];
        if (v.x | v.y | v.z | v.w) {
            int base = c * 4;
            if (v.x && base + 0 > r) { int p = atomicAdd(lcnt, 1); if (p < ELLK) loc[p] = (unsigned short)(base + 0); }
            if (v.y && base + 1 > r) { int p = atomicAdd(lcnt, 1); if (p < ELLK) loc[p] = (unsigned short)(base + 1); }
            if (v.z && base + 2 > r) { int p = atomicAdd(lcnt, 1); if (p < ELLK) loc[p] = (unsigned short)(base + 2); }
            if (v.w && base + 3 > r) { int p = atomicAdd(lcnt, 1); if (p < ELLK) loc[p] = (unsigned short)(base + 3); }
        }
    }
}

__global__ __launch_bounds__(256) void fused_stage1(const float* __restrict__ A,
                                                    const float* __restrict__ X,
                                                    const float* __restrict__ W,
                                                    unsigned short* __restrict__ Yb,
                                                    int* __restrict__ cnt,
                                                    unsigned short* __restrict__ ell) {
    if (blockIdx.x < NGEMM) {
        // ------------- MFMA GEMM: Y = X @ W (bf16 in, f32 acc, bf16 out) ------
        __shared__ unsigned short Xs[64][68];
        __shared__ unsigned short Wt[64][68];
        const int bid = blockIdx.x;
        const int m0 = (bid / (FF / BN)) * BM;
        const int n0 = (bid % (FF / BN)) * BN;
        const int t  = threadIdx.x;
        const int w  = t >> 6;
        const int l  = t & 63;
        const int lm = l & 15;
        const int lk = (l >> 4) << 2;
        f32x4 acc[4] = {};
        for (int kp = 0; kp < 4; ++kp) {
            const int kbase = kp * 64;
            __syncthreads();
            {   // stage X tile 64 rows x 64 k (f32 -> bf16)
                int row = t >> 2;
                #pragma unroll
                for (int q = 0; q < 4; ++q) {
                    int kq = (t & 3) * 4 + q * 16;
                    float4 v = *reinterpret_cast<const float4*>(X + (size_t)(m0 + row) * FF + kbase + kq);
                    ushort4 b = { f2bf(v.x), f2bf(v.y), f2bf(v.z), f2bf(v.w) };
                    *reinterpret_cast<ushort4*>(&Xs[row][kq]) = b;
                }
            }
            {   // stage W^T tile: Wt[n][k] from W[k][n]
                int n4 = (t & 15) * 4;
                int kk = t >> 4;
                #pragma unroll
                for (int q = 0; q < 4; ++q) {
                    int k = kk + q * 16;
                    float4 v = *reinterpret_cast<const float4*>(W + (size_t)(kbase + k) * FF + n0 + n4);
                    Wt[n4 + 0][k] = f2bf(v.x);
                    Wt[n4 + 1][k] = f2bf(v.y);
                    Wt[n4 + 2][k] = f2bf(v.z);
                    Wt[n4 + 3][k] = f2bf(v.w);
                }
            }
            __syncthreads();
            #pragma unroll
            for (int ks = 0; ks < 2; ++ks) {
                const int k0 = ks * 32;
                union { bf16x8 v; uint2 u[2]; } af;
                af.u[0] = *reinterpret_cast<const uint2*>(&Xs[w * 16 + lm][k0 + lk]);
                af.u[1] = *reinterpret_cast<const uint2*>(&Xs[w * 16 + lm][k0 + 16 + lk]);
                #pragma unroll
                for (int f = 0; f < 4; ++f) {
                    union { bf16x8 v; uint2 u[2]; } bf;
                    bf.u[0] = *reinterpret_cast<const uint2*>(&Wt[f * 16 + lm][k0 + lk]);
                    bf.u[1] = *reinterpret_cast<const uint2*>(&Wt[f * 16 + lm][k0 + 16 + lk]);
                    acc[f] = __builtin_amdgcn_mfma_f32_16x16x32_bf16(af.v, bf.v, acc[f], 0, 0, 0);
                }
            }
        }
        #pragma unroll
        for (int f = 0; f < 4; ++f) {
            #pragma unroll
            for (int r = 0; r < 4; ++r) {
                int row = m0 + w * 16 + lk + r;
                int col = n0 + f * 16 + lm;
                Yb[(size_t)row * FF + col] = f2bf(acc[f][r]);
            }
        }
    } else {
        // ------------- upper-triangle scan of row pair (s, 8191-s) -----------
        __shared__ unsigned short loc0[ELLK], loc1[ELLK];
        __shared__ int lc0, lc1, base0, base1;
        const int s  = blockIdx.x - NGEMM;
        const int r0 = s;
        const int r1 = NN - 1 - s;
        if (threadIdx.x == 0) { lc0 = 0; lc1 = 0; }
        __syncthreads();
        scan_row_upper(A, r0, loc0, &lc0);
        scan_row_upper(A, r1, loc1, &lc1);
        __syncthreads();
        const int n0 = lc0 < ELLK ? lc0 : ELLK;
        const int n1 = lc1 < ELLK ? lc1 : ELLK;
        if (threadIdx.x == 0) base0 = atomicAdd(&cnt[r0], n0);
        if (threadIdx.x == 1) base1 = atomicAdd(&cnt[r1], n1);
        __syncthreads();
        for (int t = threadIdx.x; t < n0; t += 256) {
            int p = base0 + t;
            if (p < ELLK) ell[(size_t)r0 * ELLK + p] = loc0[t];
        }
        for (int t = threadIdx.x; t < n1; t += 256) {
            int p = base1 + t;
            if (p < ELLK) ell[(size_t)r1 * ELLK + p] = loc1[t];
        }
        for (int t = threadIdx.x; t < n0; t += 256) {
            int j = loc0[t];
            int q = atomicAdd(&cnt[j], 1);
            if (q < ELLK) ell[(size_t)j * ELLK + q] = (unsigned short)r0;
        }
        for (int t = threadIdx.x; t < n1; t += 256) {
            int j = loc1[t];
            int q = atomicAdd(&cnt[j], 1);
            if (q < ELLK) ell[(size_t)j * ELLK + q] = (unsigned short)r1;
        }
    }
}

// ---- Stage 2: one row per block; 4 waves split the neighbor list ------------
__global__ __launch_bounds__(256) void spmm_kernel(const unsigned short* __restrict__ Yb,
                                                   const int* __restrict__ cnt,
                                                   const unsigned short* __restrict__ ell,
                                                   const float* __restrict__ bias,
                                                   float* __restrict__ out) {
    const int row  = blockIdx.x;
    const int tid  = threadIdx.x;
    const int wave = tid >> 6;
    const int lane = tid & 63;
    __shared__ unsigned short sidx[ELLK];
    __shared__ float sdj[ELLK];
    __shared__ float part[4][FF];
    int c = cnt[row];
    c = c < ELLK ? c : ELLK;
    if (tid < c) {
        int j = ell[(size_t)row * ELLK + tid];
        sidx[tid] = (unsigned short)j;
        sdj[tid]  = rsqrtf((float)(cnt[j] + 1));
    }
    __syncthreads();
    // each wave handles neighbors t = wave, wave+4, ... (chain length ~c/4)
    float a0 = 0.f, a1 = 0.f, a2 = 0.f, a3 = 0.f;
    for (int t = wave; t < c; t += 4) {
        int j = sidx[t];
        float dj = sdj[t];
        ushort4 v = *reinterpret_cast<const ushort4*>(Yb + (size_t)j * FF + lane * 4);
        a0 = fmaf(dj, bf2f(v.x), a0);
        a1 = fmaf(dj, bf2f(v.y), a1);
        a2 = fmaf(dj, bf2f(v.z), a2);
        a3 = fmaf(dj, bf2f(v.w), a3);
    }
    part[wave][lane * 4 + 0] = a0;
    part[wave][lane * 4 + 1] = a1;
    part[wave][lane * 4 + 2] = a2;
    part[wave][lane * 4 + 3] = a3;
    __syncthreads();
    // reduce: thread f handles feature f
    const float di = rsqrtf((float)(c + 1));
    float sum = part[0][tid] + part[1][tid] + part[2][tid] + part[3][tid];
    sum = fmaf(di, bf2f(Yb[(size_t)row * FF + tid]), sum);   // self-loop d_i*Y_i
    out[(size_t)row * FF + tid] = fmaf(di, sum, bias[tid]);
}

extern "C" void kernel_launch(void* const* d_in, const int* in_sizes, int n_in,
                              void* d_out, int out_size, void* d_ws, size_t ws_size,
                              hipStream_t stream) {
    const float* A    = (const float*)d_in[0];   // [8192,8192]
    const float* X    = (const float*)d_in[1];   // [8192,256]
    const float* W    = (const float*)d_in[2];   // [256,256]
    const float* bias = (const float*)d_in[3];   // [256]
    float* out = (float*)d_out;                  // [8192,256]

    // workspace: Yb 4 MiB | cnt 32 KiB | ell 2 MiB
    char* ws = (char*)d_ws;
    unsigned short* Yb  = (unsigned short*)(ws);
    int*            cnt = (int*)(ws + (size_t)NN * FF * 2);
    unsigned short* ell = (unsigned short*)(ws + (size_t)NN * FF * 2 + NN * 4);

    hipMemsetAsync(cnt, 0, NN * sizeof(int), stream);

    fused_stage1<<<NGEMM + NSCAN, 256, 0, stream>>>(A, X, W, Yb, cnt, ell);
    // launched twice ON PURPOSE this round: idempotent second pass measures
    // spmm's exact cost via dur_us delta (removed next round).
    spmm_kernel<<<NN, 256, 0, stream>>>(Yb, cnt, ell, bias, out);
    spmm_kernel<<<NN, 256, 0, stream>>>(Yb, cnt, ell, bias, out);
}

// Round 12
// 65.260 us; speedup vs baseline: 1.2325x; 1.2325x over previous
//
#include <hip/hip_runtime.h>
#include <hip/hip_bf16.h>
#include <cstdint>

// out = D^-1/2 (I+A) D^-1/2 X W + b ; N=8192, F=256, ~33 nnz/row, A symmetric.
// Stage 1 (fused): [MFMA GEMM Y=X@W -> bf16, 512 blocks at grid head] ||
//   [upper-triangle A-scan, ATOMIC-FREE: each row owned by one block, forward
//    list + count stored directly (no reservation, no inline mirror)].
// Stage 1.6 (mirror): one wave per row scatters mirror edges (j<-r) with
//   dedicated atomics - contention isolated from the A stream.
// Stage 2: wave-per-row gather (R10 form); degree = fcnt[j]+mcnt[j].

#define NN 8192
#define FF 256
#define ELLK 128
#define BM 64
#define BN 64
#define NGEMM ((NN / BM) * (FF / BN))   // 512 gemm blocks
#define NSCAN (NN / 2)                  // 4096 scan blocks (row pairs)

typedef short bf16x8 __attribute__((ext_vector_type(8)));
typedef float f32x4  __attribute__((ext_vector_type(4)));

__device__ __forceinline__ float bf2f(unsigned short u) {
    union { unsigned int i; float f; } c; c.i = ((unsigned int)u) << 16; return c.f;
}
__device__ __forceinline__ unsigned short f2bf(float f) {
    union { float f; unsigned int i; } c; c.f = f;
    unsigned int r = c.i + 0x7FFF + ((c.i >> 16) & 1);   // round-to-nearest-even
    return (unsigned short)(r >> 16);
}

// stream row r's strict upper triangle (j > r), appending hits to LDS list
__device__ __forceinline__ void scan_row_upper(const float* __restrict__ A, int r,
                                               unsigned short* __restrict__ loc,
                                               int* __restrict__ lcnt) {
    const uint4* Arow = reinterpret_cast<const uint4*>(A + (size_t)r * NN);
    const int c0 = (r + 1) >> 2;
    for (int c = c0 + threadIdx.x; c < NN / 4; c += 256) {
        uint4 v = Arow[c];
        if (v.x | v.y | v.z | v.w) {
            int base = c * 4;
            if (v.x && base + 0 > r) { int p = atomicAdd(lcnt, 1); if (p < ELLK) loc[p] = (unsigned short)(base + 0); }
            if (v.y && base + 1 > r) { int p = atomicAdd(lcnt, 1); if (p < ELLK) loc[p] = (unsigned short)(base + 1); }
            if (v.z && base + 2 > r) { int p = atomicAdd(lcnt, 1); if (p < ELLK) loc[p] = (unsigned short)(base + 2); }
            if (v.w && base + 3 > r) { int p = atomicAdd(lcnt, 1); if (p < ELLK) loc[p] = (unsigned short)(base + 3); }
        }
    }
}

__global__ __launch_bounds__(256) void fused_stage1(const float* __restrict__ A,
                                                    const float* __restrict__ X,
                                                    const float* __restrict__ W,
                                                    unsigned short* __restrict__ Yb,
                                                    int* __restrict__ fcnt,
                                                    unsigned short* __restrict__ ell) {
    if (blockIdx.x < NGEMM) {
        // ------------- MFMA GEMM: Y = X @ W (bf16 in, f32 acc, bf16 out) ------
        __shared__ unsigned short Xs[64][68];
        __shared__ unsigned short Wt[64][68];
        const int bid = blockIdx.x;
        const int m0 = (bid / (FF / BN)) * BM;
        const int n0 = (bid % (FF / BN)) * BN;
        const int t  = threadIdx.x;
        const int w  = t >> 6;
        const int l  = t & 63;
        const int lm = l & 15;
        const int lk = (l >> 4) << 2;
        f32x4 acc[4] = {};
        for (int kp = 0; kp < 4; ++kp) {
            const int kbase = kp * 64;
            __syncthreads();
            {   // stage X tile 64 rows x 64 k (f32 -> bf16)
                int row = t >> 2;
                #pragma unroll
                for (int q = 0; q < 4; ++q) {
                    int kq = (t & 3) * 4 + q * 16;
                    float4 v = *reinterpret_cast<const float4*>(X + (size_t)(m0 + row) * FF + kbase + kq);
                    ushort4 b = { f2bf(v.x), f2bf(v.y), f2bf(v.z), f2bf(v.w) };
                    *reinterpret_cast<ushort4*>(&Xs[row][kq]) = b;
                }
            }
            {   // stage W^T tile: Wt[n][k] from W[k][n]
                int n4 = (t & 15) * 4;
                int kk = t >> 4;
                #pragma unroll
                for (int q = 0; q < 4; ++q) {
                    int k = kk + q * 16;
                    float4 v = *reinterpret_cast<const float4*>(W + (size_t)(kbase + k) * FF + n0 + n4);
                    Wt[n4 + 0][k] = f2bf(v.x);
                    Wt[n4 + 1][k] = f2bf(v.y);
                    Wt[n4 + 2][k] = f2bf(v.z);
                    Wt[n4 + 3][k] = f2bf(v.w);
                }
            }
            __syncthreads();
            #pragma unroll
            for (int ks = 0; ks < 2; ++ks) {
                const int k0 = ks * 32;
                union { bf16x8 v; uint2 u[2]; } af;
                af.u[0] = *reinterpret_cast<const uint2*>(&Xs[w * 16 + lm][k0 + lk]);
                af.u[1] = *reinterpret_cast<const uint2*>(&Xs[w * 16 + lm][k0 + 16 + lk]);
                #pragma unroll
                for (int f = 0; f < 4; ++f) {
                    union { bf16x8 v; uint2 u[2]; } bf;
                    bf.u[0] = *reinterpret_cast<const uint2*>(&Wt[f * 16 + lm][k0 + lk]);
                    bf.u[1] = *reinterpret_cast<const uint2*>(&Wt[f * 16 + lm][k0 + 16 + lk]);
                    acc[f] = __builtin_amdgcn_mfma_f32_16x16x32_bf16(af.v, bf.v, acc[f], 0, 0, 0);
                }
            }
        }
        #pragma unroll
        for (int f = 0; f < 4; ++f) {
            #pragma unroll
            for (int r = 0; r < 4; ++r) {
                int row = m0 + w * 16 + lk + r;
                int col = n0 + f * 16 + lm;
                Yb[(size_t)row * FF + col] = f2bf(acc[f][r]);
            }
        }
    } else {
        // ------------- upper-triangle scan of row pair (s, 8191-s) -----------
        // each row owned by exactly one block -> NO global atomics anywhere
        __shared__ unsigned short loc0[ELLK], loc1[ELLK];
        __shared__ int lc0, lc1;
        const int s  = blockIdx.x - NGEMM;
        const int r0 = s;
        const int r1 = NN - 1 - s;
        if (threadIdx.x == 0) { lc0 = 0; lc1 = 0; }
        __syncthreads();
        scan_row_upper(A, r0, loc0, &lc0);
        scan_row_upper(A, r1, loc1, &lc1);
        __syncthreads();
        const int n0 = lc0 < ELLK ? lc0 : ELLK;
        const int n1 = lc1 < ELLK ? lc1 : ELLK;
        if (threadIdx.x == 0) fcnt[r0] = n0;
        if (threadIdx.x == 1) fcnt[r1] = n1;
        for (int t = threadIdx.x; t < n0; t += 256)
            ell[(size_t)r0 * ELLK + t] = loc0[t];
        for (int t = threadIdx.x; t < n1; t += 256)
            ell[(size_t)r1 * ELLK + t] = loc1[t];
    }
}

// ---- Stage 1.6: mirror scatter, one wave per row ----------------------------
__global__ __launch_bounds__(256) void mirror_kernel(const int* __restrict__ fcnt,
                                                     int* __restrict__ mcnt,
                                                     unsigned short* __restrict__ ell) {
    const int wave = threadIdx.x >> 6;
    const int lane = threadIdx.x & 63;
    const int row  = blockIdx.x * 4 + wave;
    const int n = fcnt[row];
    for (int t = lane; t < n; t += 64) {
        int j = ell[(size_t)row * ELLK + t];
        int p = atomicAdd(&mcnt[j], 1);
        int q = fcnt[j] + p;
        if (q < ELLK) ell[(size_t)j * ELLK + q] = (unsigned short)row;
    }
}

// ---- Stage 2: wave-per-row normalized aggregation over bf16 Y ---------------
__global__ __launch_bounds__(256) void spmm_kernel(const unsigned short* __restrict__ Yb,
                                                   const int* __restrict__ fcnt,
                                                   const int* __restrict__ mcnt,
                                                   const unsigned short* __restrict__ ell,
                                                   const float* __restrict__ bias,
                                                   float* __restrict__ out) {
    const int wave = threadIdx.x >> 6;
    const int lane = threadIdx.x & 63;
    const int row = blockIdx.x * 4 + wave;
    __shared__ unsigned short sidx[4][ELLK];
    __shared__ float sdj[4][ELLK];
    int c = fcnt[row] + mcnt[row];
    c = c < ELLK ? c : ELLK;
    for (int t = lane; t < c; t += 64) {
        int j = ell[(size_t)row * ELLK + t];
        sidx[wave][t] = (unsigned short)j;
        sdj[wave][t]  = rsqrtf((float)(fcnt[j] + mcnt[j] + 1));
    }
    __syncthreads();
    const float di = rsqrtf((float)(c + 1));
    ushort4 ys = *reinterpret_cast<const ushort4*>(Yb + (size_t)row * FF + lane * 4);
    float a0 = di * bf2f(ys.x), a1 = di * bf2f(ys.y);
    float a2 = di * bf2f(ys.z), a3 = di * bf2f(ys.w);
    for (int t = 0; t < c; ++t) {
        int j = sidx[wave][t];
        float dj = sdj[wave][t];
        ushort4 v = *reinterpret_cast<const ushort4*>(Yb + (size_t)j * FF + lane * 4);
        a0 = fmaf(dj, bf2f(v.x), a0);
        a1 = fmaf(dj, bf2f(v.y), a1);
        a2 = fmaf(dj, bf2f(v.z), a2);
        a3 = fmaf(dj, bf2f(v.w), a3);
    }
    float4 b4 = *reinterpret_cast<const float4*>(bias + lane * 4);
    float4 o;
    o.x = fmaf(di, a0, b4.x);
    o.y = fmaf(di, a1, b4.y);
    o.z = fmaf(di, a2, b4.z);
    o.w = fmaf(di, a3, b4.w);
    *reinterpret_cast<float4*>(out + (size_t)row * FF + lane * 4) = o;
}

extern "C" void kernel_launch(void* const* d_in, const int* in_sizes, int n_in,
                              void* d_out, int out_size, void* d_ws, size_t ws_size,
                              hipStream_t stream) {
    const float* A    = (const float*)d_in[0];   // [8192,8192]
    const float* X    = (const float*)d_in[1];   // [8192,256]
    const float* W    = (const float*)d_in[2];   // [256,256]
    const float* bias = (const float*)d_in[3];   // [256]
    float* out = (float*)d_out;                  // [8192,256]

    // workspace: Yb 4 MiB | fcnt 32 KiB | mcnt 32 KiB | ell 2 MiB
    char* ws = (char*)d_ws;
    unsigned short* Yb   = (unsigned short*)(ws);
    int*            fcnt = (int*)(ws + (size_t)NN * FF * 2);
    int*            mcnt = (int*)(ws + (size_t)NN * FF * 2 + NN * 4);
    unsigned short* ell  = (unsigned short*)(ws + (size_t)NN * FF * 2 + NN * 8);

    // only the mirror counters need zeroing (fcnt is plain-stored per row)
    hipMemsetAsync(mcnt, 0, NN * sizeof(int), stream);

    fused_stage1<<<NGEMM + NSCAN, 256, 0, stream>>>(A, X, W, Yb, fcnt, ell);
    mirror_kernel<<<NN / 4, 256, 0, stream>>>(fcnt, mcnt, ell);
    spmm_kernel<<<NN / 4, 256, 0, stream>>>(Yb, fcnt, mcnt, ell, bias, out);
}

// Round 13
// 54.489 us; speedup vs baseline: 1.4761x; 1.1977x over previous
//
#include <hip/hip_runtime.h>
#include <hip/hip_bf16.h>
#include <cstdint>

// out = D^-1/2 (I+A) D^-1/2 X W + b ; N=8192, F=256, ~33 nnz/row, A symmetric.
// Stage 1 (fused): [MFMA GEMM Y=X@W -> bf16, 512 blocks at grid head] ||
//   [upper-triangle A-scan, ONE ROW PER BLOCK in natural (LPT) order:
//    block b-512 scans row b-512's upper triangle into LDS; at block end:
//    one atomic reserves the forward slot range, coalesced dump, then the
//    batched mirror scatter (hidden under the stream - R9/R10 proven).]
// Stage 2: wave-per-row gather (R10 exact form).

#define NN 8192
#define FF 256
#define ELLK 128
#define BM 64
#define BN 64
#define NGEMM ((NN / BM) * (FF / BN))   // 512 gemm blocks

typedef short bf16x8 __attribute__((ext_vector_type(8)));
typedef float f32x4  __attribute__((ext_vector_type(4)));

__device__ __forceinline__ float bf2f(unsigned short u) {
    union { unsigned int i; float f; } c; c.i = ((unsigned int)u) << 16; return c.f;
}
__device__ __forceinline__ unsigned short f2bf(float f) {
    union { float f; unsigned int i; } c; c.f = f;
    unsigned int r = c.i + 0x7FFF + ((c.i >> 16) & 1);   // round-to-nearest-even
    return (unsigned short)(r >> 16);
}

__global__ __launch_bounds__(256) void fused_stage1(const float* __restrict__ A,
                                                    const float* __restrict__ X,
                                                    const float* __restrict__ W,
                                                    unsigned short* __restrict__ Yb,
                                                    int* __restrict__ cnt,
                                                    unsigned short* __restrict__ ell) {
    if (blockIdx.x < NGEMM) {
        // ------------- MFMA GEMM: Y = X @ W (bf16 in, f32 acc, bf16 out) ------
        __shared__ unsigned short Xs[64][68];
        __shared__ unsigned short Wt[64][68];
        const int bid = blockIdx.x;
        const int m0 = (bid / (FF / BN)) * BM;
        const int n0 = (bid % (FF / BN)) * BN;
        const int t  = threadIdx.x;
        const int w  = t >> 6;
        const int l  = t & 63;
        const int lm = l & 15;
        const int lk = (l >> 4) << 2;
        f32x4 acc[4] = {};
        for (int kp = 0; kp < 4; ++kp) {
            const int kbase = kp * 64;
            __syncthreads();
            {   // stage X tile 64 rows x 64 k (f32 -> bf16)
                int row = t >> 2;
                #pragma unroll
                for (int q = 0; q < 4; ++q) {
                    int kq = (t & 3) * 4 + q * 16;
                    float4 v = *reinterpret_cast<const float4*>(X + (size_t)(m0 + row) * FF + kbase + kq);
                    ushort4 b = { f2bf(v.x), f2bf(v.y), f2bf(v.z), f2bf(v.w) };
                    *reinterpret_cast<ushort4*>(&Xs[row][kq]) = b;
                }
            }
            {   // stage W^T tile: Wt[n][k] from W[k][n]
                int n4 = (t & 15) * 4;
                int kk = t >> 4;
                #pragma unroll
                for (int q = 0; q < 4; ++q) {
                    int k = kk + q * 16;
                    float4 v = *reinterpret_cast<const float4*>(W + (size_t)(kbase + k) * FF + n0 + n4);
                    Wt[n4 + 0][k] = f2bf(v.x);
                    Wt[n4 + 1][k] = f2bf(v.y);
                    Wt[n4 + 2][k] = f2bf(v.z);
                    Wt[n4 + 3][k] = f2bf(v.w);
                }
            }
            __syncthreads();
            #pragma unroll
            for (int ks = 0; ks < 2; ++ks) {
                const int k0 = ks * 32;
                union { bf16x8 v; uint2 u[2]; } af;
                af.u[0] = *reinterpret_cast<const uint2*>(&Xs[w * 16 + lm][k0 + lk]);
                af.u[1] = *reinterpret_cast<const uint2*>(&Xs[w * 16 + lm][k0 + 16 + lk]);
                #pragma unroll
                for (int f = 0; f < 4; ++f) {
                    union { bf16x8 v; uint2 u[2]; } bf;
                    bf.u[0] = *reinterpret_cast<const uint2*>(&Wt[f * 16 + lm][k0 + lk]);
                    bf.u[1] = *reinterpret_cast<const uint2*>(&Wt[f * 16 + lm][k0 + 16 + lk]);
                    acc[f] = __builtin_amdgcn_mfma_f32_16x16x32_bf16(af.v, bf.v, acc[f], 0, 0, 0);
                }
            }
        }
        #pragma unroll
        for (int f = 0; f < 4; ++f) {
            #pragma unroll
            for (int r = 0; r < 4; ++r) {
                int row = m0 + w * 16 + lk + r;
                int col = n0 + f * 16 + lm;
                Yb[(size_t)row * FF + col] = f2bf(acc[f][r]);
            }
        }
    } else {
        // ------------- upper-triangle scan, ONE row per block -----------------
        // block order = row order: longest rows (small r) dispatch first (LPT).
        __shared__ unsigned short loc[ELLK];
        __shared__ int lcnt, base;
        const int r = blockIdx.x - NGEMM;       // 0..8191
        if (threadIdx.x == 0) lcnt = 0;
        __syncthreads();
        const uint4* Arow = reinterpret_cast<const uint4*>(A + (size_t)r * NN);
        const int c0 = (r + 1) >> 2;            // first chunk that can hold j > r
        for (int c = c0 + threadIdx.x; c < NN / 4; c += 256) {
            uint4 v = Arow[c];
            if (v.x | v.y | v.z | v.w) {
                int b = c * 4;
                if (v.x && b + 0 > r) { int p = atomicAdd(&lcnt, 1); if (p < ELLK) loc[p] = (unsigned short)(b + 0); }
                if (v.y && b + 1 > r) { int p = atomicAdd(&lcnt, 1); if (p < ELLK) loc[p] = (unsigned short)(b + 1); }
                if (v.z && b + 2 > r) { int p = atomicAdd(&lcnt, 1); if (p < ELLK) loc[p] = (unsigned short)(b + 2); }
                if (v.w && b + 3 > r) { int p = atomicAdd(&lcnt, 1); if (p < ELLK) loc[p] = (unsigned short)(b + 3); }
            }
        }
        __syncthreads();
        const int n = lcnt < ELLK ? lcnt : ELLK;
        if (threadIdx.x == 0) base = atomicAdd(&cnt[r], n);   // forward reservation
        __syncthreads();
        for (int t = threadIdx.x; t < n; t += 256) {          // coalesced dump
            int p = base + t;
            if (p < ELLK) ell[(size_t)r * ELLK + p] = loc[t];
        }
        for (int t = threadIdx.x; t < n; t += 256) {          // batched mirror
            int j = loc[t];
            int q = atomicAdd(&cnt[j], 1);
            if (q < ELLK) ell[(size_t)j * ELLK + q] = (unsigned short)r;
        }
    }
}

// ---- Stage 2: wave-per-row normalized aggregation over bf16 Y ---------------
__global__ __launch_bounds__(256) void spmm_kernel(const unsigned short* __restrict__ Yb,
                                                   const int* __restrict__ cnt,
                                                   const unsigned short* __restrict__ ell,
                                                   const float* __restrict__ bias,
                                                   float* __restrict__ out) {
    const int wave = threadIdx.x >> 6;
    const int lane = threadIdx.x & 63;
    const int row = blockIdx.x * 4 + wave;
    __shared__ unsigned short sidx[4][ELLK];
    __shared__ float sdj[4][ELLK];
    int c = cnt[row];
    c = c < ELLK ? c : ELLK;
    for (int t = lane; t < c; t += 64) {
        int j = ell[(size_t)row * ELLK + t];
        sidx[wave][t] = (unsigned short)j;
        sdj[wave][t]  = rsqrtf((float)(cnt[j] + 1));
    }
    __syncthreads();
    const float di = rsqrtf((float)(c + 1));
    ushort4 ys = *reinterpret_cast<const ushort4*>(Yb + (size_t)row * FF + lane * 4);
    float a0 = di * bf2f(ys.x), a1 = di * bf2f(ys.y);
    float a2 = di * bf2f(ys.z), a3 = di * bf2f(ys.w);
    for (int t = 0; t < c; ++t) {
        int j = sidx[wave][t];
        float dj = sdj[wave][t];
        ushort4 v = *reinterpret_cast<const ushort4*>(Yb + (size_t)j * FF + lane * 4);
        a0 = fmaf(dj, bf2f(v.x), a0);
        a1 = fmaf(dj, bf2f(v.y), a1);
        a2 = fmaf(dj, bf2f(v.z), a2);
        a3 = fmaf(dj, bf2f(v.w), a3);
    }
    float4 b4 = *reinterpret_cast<const float4*>(bias + lane * 4);
    float4 o;
    o.x = fmaf(di, a0, b4.x);
    o.y = fmaf(di, a1, b4.y);
    o.z = fmaf(di, a2, b4.z);
    o.w = fmaf(di, a3, b4.w);
    *reinterpret_cast<float4*>(out + (size_t)row * FF + lane * 4) = o;
}

extern "C" void kernel_launch(void* const* d_in, const int* in_sizes, int n_in,
                              void* d_out, int out_size, void* d_ws, size_t ws_size,
                              hipStream_t stream) {
    const float* A    = (const float*)d_in[0];   // [8192,8192]
    const float* X    = (const float*)d_in[1];   // [8192,256]
    const float* W    = (const float*)d_in[2];   // [256,256]
    const float* bias = (const float*)d_in[3];   // [256]
    float* out = (float*)d_out;                  // [8192,256]

    // workspace: Yb 4 MiB | cnt 32 KiB | ell 2 MiB
    char* ws = (char*)d_ws;
    unsigned short* Yb  = (unsigned short*)(ws);
    int*            cnt = (int*)(ws + (size_t)NN * FF * 2);
    unsigned short* ell = (unsigned short*)(ws + (size_t)NN * FF * 2 + NN * 4);

    hipMemsetAsync(cnt, 0, NN * sizeof(int), stream);

    fused_stage1<<<NGEMM + NN, 256, 0, stream>>>(A, X, W, Yb, cnt, ell);
    spmm_kernel<<<NN / 4, 256, 0, stream>>>(Yb, cnt, ell, bias, out);
}